// Round 22
// baseline (1054.092 us; speedup 1.0000x reference)
//
#include <hip/hip_runtime.h>
#include <hip/hip_bf16.h>

#define NN 100000
#define NE 1600000
#define DD 64
#define NG 512
#define POOLED_F (NG * 3 * DD)   // 98304
#define STATS_F  (3 * 128)
#define SCAN_NB 196              // 196 * 512 = 100352 >= NN

typedef unsigned short u16;
typedef __attribute__((ext_vector_type(8))) short bf16x8;
typedef __attribute__((ext_vector_type(4))) float f32x4;

__device__ __forceinline__ float bf2f(u16 u) {
    return __uint_as_float(((unsigned)u) << 16);
}
__device__ __forceinline__ u16 f2bf(float f) {  // RNE
    unsigned b = __float_as_uint(f);
    return (u16)((b + 0x7FFFu + ((b >> 16) & 1u)) >> 16);
}

__global__ __launch_bounds__(256) void k_zero(float* __restrict__ p, int n) {
    int i = blockIdx.x * 256 + threadIdx.x;
    if (i < n) p[i] = 0.f;
}
__global__ __launch_bounds__(256) void k_zeroi(int* __restrict__ p, int n) {
    int i = blockIdx.x * 256 + threadIdx.x;
    if (i < n) p[i] = 0;
}
__global__ __launch_bounds__(256) void k_sentinel(float* out, float val) {
    if (threadIdx.x == 0 && blockIdx.x == 0) out[0] = val;
}
// f32 -> bf16 mirror (for gather-friendly h)
__global__ __launch_bounds__(256) void k_cvt16(const float* __restrict__ src,
                                               u16* __restrict__ dst) {
    int total = NN * DD / 4;
    for (int i = blockIdx.x * 256 + threadIdx.x; i < total; i += gridDim.x * 256) {
        float4 t = ((const float4*)src)[i];
        ushort4 u;
        u.x = f2bf(t.x); u.y = f2bf(t.y); u.z = f2bf(t.z); u.w = f2bf(t.w);
        ((ushort4*)dst)[i] = u;
    }
}

// ---------------------------------------------------------------- CSR build
__global__ __launch_bounds__(256) void k_hist(const int* __restrict__ dst,
                                              int* __restrict__ counts) {
    int e = blockIdx.x * 256 + threadIdx.x;
    if (e < NE) atomicAdd(&counts[dst[e]], 1);
}

__global__ __launch_bounds__(512) void k_scanA(const int* __restrict__ counts,
                                               int* __restrict__ bsum) {
    __shared__ int red[512];
    int tid = threadIdx.x;
    int idx = blockIdx.x * 512 + tid;
    red[tid] = (idx < NN) ? counts[idx] : 0;
    __syncthreads();
    for (int w = 256; w > 0; w >>= 1) {
        if (tid < w) red[tid] += red[tid + w];
        __syncthreads();
    }
    if (tid == 0) bsum[blockIdx.x] = red[0];
}

__global__ __launch_bounds__(256) void k_scanB(const int* __restrict__ bsum,
                                               int* __restrict__ boff,
                                               int* __restrict__ rowptr) {
    __shared__ int sh[256];
    int tid = threadIdx.x;
    int v = (tid < SCAN_NB) ? bsum[tid] : 0;
    sh[tid] = v;
    __syncthreads();
    for (int off = 1; off < 256; off <<= 1) {
        int t = (tid >= off) ? sh[tid - off] : 0;
        __syncthreads();
        sh[tid] += t;
        __syncthreads();
    }
    if (tid < SCAN_NB) boff[tid] = sh[tid] - v;   // exclusive
    if (tid == SCAN_NB - 1) rowptr[NN] = sh[tid]; // total
}

__global__ __launch_bounds__(512) void k_scanC(const int* __restrict__ counts,
                                               const int* __restrict__ boff,
                                               int* __restrict__ rowptr,
                                               int* __restrict__ cursor) {
    __shared__ int sh[512];
    int tid = threadIdx.x;
    int idx = blockIdx.x * 512 + tid;
    int v = (idx < NN) ? counts[idx] : 0;
    sh[tid] = v;
    __syncthreads();
    for (int off = 1; off < 512; off <<= 1) {
        int t = (tid >= off) ? sh[tid - off] : 0;
        __syncthreads();
        sh[tid] += t;
        __syncthreads();
    }
    if (idx < NN) {
        int r = boff[blockIdx.x] + sh[tid] - v;
        rowptr[idx] = r;
        cursor[idx] = r;
    }
}

__global__ __launch_bounds__(256) void k_scatter(const int* __restrict__ src,
                                                 const int* __restrict__ dst,
                                                 int* __restrict__ cursor,
                                                 int* __restrict__ epos,
                                                 int* __restrict__ psrc) {
    int e = blockIdx.x * 256 + threadIdx.x;
    if (e >= NE) return;
    int pos = atomicAdd(&cursor[dst[e]], 1);
    epos[e] = pos;
    psrc[pos] = src[e];
}

// --------------------------------------------- fused 3-layer msg GEMM, MFMA
// software-pipelined (r20-proven: 277 -> 243 us)
__global__ __launch_bounds__(256) void k_fmsg(
    const float* __restrict__ ea, const float* __restrict__ We,
    const float* __restrict__ be, const int* __restrict__ epos,
    u16* __restrict__ msgb)
{
    __shared__ u16 stage[4][16][72];   // 9216 B; row stride 144 B (16B-mult)
    int tid = threadIdx.x;
    int wv = tid >> 6, lane = tid & 63;
    int lg = lane >> 4, lr = lane & 15;

    bf16x8 wf[3][4][2];
    float bias[3][4];
#pragma unroll
    for (int l = 0; l < 3; ++l)
#pragma unroll
        for (int cb = 0; cb < 4; ++cb) {
#pragma unroll
            for (int kh = 0; kh < 2; ++kh) {
                bf16x8 f;
#pragma unroll
                for (int j = 0; j < 8; ++j) {
                    int k = kh * 32 + lg * 8 + j;
                    f[j] = (short)f2bf(We[l * 4096 + k * 64 + cb * 16 + lr]);
                }
                wf[l][cb][kh] = f;
            }
            bias[l][cb] = be[l * 64 + cb * 16 + lr];
        }

    const int ngroups = NE / 16;   // 100000
    const int stride = gridDim.x * 4;
    int g = blockIdx.x * 4 + wv;
    if (g >= ngroups) return;

    float4 t0a, t1a, t0b, t1b;
    {
        const float4* ap =
            (const float4*)(ea + (size_t)((g * 16) + lr) * DD + lg * 8);
        t0a = ap[0]; t1a = ap[1];          // kh = 0
        t0b = ap[8]; t1b = ap[9];          // kh = 1
    }

    while (g < ngroups) {
        int gn = g + stride;
        bf16x8 af[2];
        {
            bf16x8 f;
            f[0] = (short)f2bf(t0a.x); f[1] = (short)f2bf(t0a.y);
            f[2] = (short)f2bf(t0a.z); f[3] = (short)f2bf(t0a.w);
            f[4] = (short)f2bf(t1a.x); f[5] = (short)f2bf(t1a.y);
            f[6] = (short)f2bf(t1a.z); f[7] = (short)f2bf(t1a.w);
            af[0] = f;
            f[0] = (short)f2bf(t0b.x); f[1] = (short)f2bf(t0b.y);
            f[2] = (short)f2bf(t0b.z); f[3] = (short)f2bf(t0b.w);
            f[4] = (short)f2bf(t1b.x); f[5] = (short)f2bf(t1b.y);
            f[6] = (short)f2bf(t1b.z); f[7] = (short)f2bf(t1b.w);
            af[1] = f;
        }
        if (gn < ngroups) {
            const float4* ap =
                (const float4*)(ea + (size_t)((gn * 16) + lr) * DD + lg * 8);
            t0a = ap[0]; t1a = ap[1];
            t0b = ap[8]; t1b = ap[9];
        }

        int ebase = g * 16;
#pragma unroll
        for (int l = 0; l < 3; ++l) {
#pragma unroll
            for (int cb = 0; cb < 4; ++cb) {
                f32x4 acc = {0.f, 0.f, 0.f, 0.f};
                acc = __builtin_amdgcn_mfma_f32_16x16x32_bf16(
                          af[0], wf[l][cb][0], acc, 0, 0, 0);
                acc = __builtin_amdgcn_mfma_f32_16x16x32_bf16(
                          af[1], wf[l][cb][1], acc, 0, 0, 0);
#pragma unroll
                for (int i = 0; i < 4; ++i)
                    stage[wv][lg * 4 + i][cb * 16 + lr] =
                        f2bf(acc[i] + bias[l][cb]);
            }
#pragma unroll
            for (int p = 0; p < 2; ++p) {
                int row = p * 8 + (lane >> 3), chunk = lane & 7;
                uint4 v = *(const uint4*)&stage[wv][row][chunk * 8];
                int pos = epos[ebase + row];
                *(uint4*)(msgb + ((size_t)l * NE + pos) * DD + chunk * 8) = v;
            }
        }
        g = gn;
    }
}

// ---------------------------------------------------------------- aggregate
// unroll 4 (proven best); gathered h rows now bf16 (2 cache lines, not 4)
__global__ __launch_bounds__(256) void k_agg(
    const u16* __restrict__ msgb, const float* __restrict__ hf,
    const u16* __restrict__ hb,
    const int* __restrict__ rowptr, const int* __restrict__ psrc,
    float* __restrict__ agg)
{
    int node = (blockIdx.x * 256 + threadIdx.x) >> 6;
    int lane = threadIdx.x & 63;
    if (node >= NN) return;
    int beg = rowptr[node], end = rowptr[node + 1];
    float acc = hf[(size_t)node * DD + lane];    // self term: f32, coalesced
    int j = beg;
    for (; j + 3 < end; j += 4) {
        int s0 = psrc[j], s1 = psrc[j + 1], s2 = psrc[j + 2], s3 = psrc[j + 3];
        float m0 = bf2f(hb[(size_t)s0 * DD + lane]) + bf2f(msgb[(size_t)j * DD + lane]);
        float m1 = bf2f(hb[(size_t)s1 * DD + lane]) + bf2f(msgb[(size_t)(j + 1) * DD + lane]);
        float m2 = bf2f(hb[(size_t)s2 * DD + lane]) + bf2f(msgb[(size_t)(j + 2) * DD + lane]);
        float m3 = bf2f(hb[(size_t)s3 * DD + lane]) + bf2f(msgb[(size_t)(j + 3) * DD + lane]);
        acc += fmaxf(m0, 0.f) + fmaxf(m1, 0.f) + fmaxf(m2, 0.f) + fmaxf(m3, 0.f);
    }
    for (; j < end; ++j) {
        int s = psrc[j];
        acc += fmaxf(bf2f(hb[(size_t)s * DD + lane]) + bf2f(msgb[(size_t)j * DD + lane]), 0.f);
    }
    agg[(size_t)node * DD + lane] = acc;
}

// ---------------- MLP (lane=channel, W in LDS) with fused BN stats
__global__ __launch_bounds__(256) void k_mlp_stats(
    const float* __restrict__ in,
    const float* __restrict__ W1, const float* __restrict__ b1,
    const float* __restrict__ W2, const float* __restrict__ b2,
    float* __restrict__ z, float* __restrict__ stats)
{
    __shared__ __align__(16) float W1l[DD * DD];   // [k*64 + c]
    __shared__ __align__(16) float W2l[DD * DD];
    __shared__ float zin[4][DD];
    __shared__ float red[512];
    int tid = threadIdx.x, wv = tid >> 6, lane = tid & 63;
    for (int i = tid; i < DD * DD / 4; i += 256) {
        ((float4*)W1l)[i] = ((const float4*)W1)[i];
        ((float4*)W2l)[i] = ((const float4*)W2)[i];
    }
    float b1c = b1[lane], b2c = b2[lane];
    __syncthreads();

    float s = 0.f, s2 = 0.f;
    int wid = blockIdx.x * 4 + wv, nw = gridDim.x * 4;
    for (int node = wid; node < NN; node += nw) {
        zin[wv][lane] = in[(size_t)node * DD + lane];   // wave-local broadcast
        float z1 = b1c;
#pragma unroll
        for (int k = 0; k < DD; ++k)
            z1 = fmaf(zin[wv][k], W1l[k * DD + lane], z1);
        z1 = fmaxf(z1, 0.f);
        zin[wv][lane] = z1;                              // in-wave ordered
        float z2 = b2c;
#pragma unroll
        for (int k = 0; k < DD; ++k)
            z2 = fmaf(zin[wv][k], W2l[k * DD + lane], z2);
        z2 = fmaxf(z2, 0.f);
        z[(size_t)node * DD + lane] = z2;
        s += z2;
        s2 = fmaf(z2, z2, s2);
    }
    red[tid] = s; red[256 + tid] = s2;
    __syncthreads();
    if (tid < 64) {
        float a = red[tid] + red[64 + tid] + red[128 + tid] + red[192 + tid];
        float b = red[256 + tid] + red[320 + tid] + red[384 + tid] + red[448 + tid];
        atomicAdd(&stats[tid], a);
        atomicAdd(&stats[64 + tid], b);
    }
}

// ------------------- norm + pool; writes f32 h (d_out) AND bf16 mirror (ws)
__global__ __launch_bounds__(256) void k_norm_pool(
    const float* __restrict__ z, const float* __restrict__ stats,
    const float* __restrict__ gamma, const float* __restrict__ beta,
    const int* __restrict__ batch, float* __restrict__ hout,
    u16* __restrict__ hb16, float* __restrict__ pooled, int l)
{
    int wave = (blockIdx.x * 256 + threadIdx.x) >> 6;
    int lane = threadIdx.x & 63;
    int n0 = wave * 64;
    if (n0 >= NN) return;
    int n1 = n0 + 64; if (n1 > NN) n1 = NN;

    float mu  = stats[lane] * (1.0f / NN);
    float var = stats[64 + lane] * (1.0f / NN) - mu * mu;
    float rstd = rsqrtf(var + 1e-5f);
    float sc = gamma[l * DD + lane] * rstd;
    float sh = beta[l * DD + lane] - sc * mu;

    int gcur = batch[n0];
    float acc = 0.f;
    for (int n = n0; n < n1; ++n) {
        float hv = fmaf(z[(size_t)n * DD + lane], sc, sh);
        hout[(size_t)n * DD + lane] = hv;
        hb16[(size_t)n * DD + lane] = f2bf(hv);
        int g = batch[n];
        if (g != gcur) {
            atomicAdd(&pooled[(size_t)gcur * (3 * DD) + l * DD + lane], acc);
            gcur = g; acc = 0.f;
        }
        acc += hv;
    }
    atomicAdd(&pooled[(size_t)gcur * (3 * DD) + l * DD + lane], acc);
}

// ---------------------------------------------------------------- fallback
__global__ __launch_bounds__(256) void k_copy(const float* __restrict__ src,
                                              float* __restrict__ agg) {
    int total = NN * DD / 4;
    for (int i = blockIdx.x * 256 + threadIdx.x; i < total; i += gridDim.x * 256)
        ((float4*)agg)[i] = ((const float4*)src)[i];
}
__global__ __launch_bounds__(256) void k_edge(
    const float* __restrict__ ea, const float* __restrict__ h,
    const float* __restrict__ W, const float* __restrict__ bias,
    const int* __restrict__ src, const int* __restrict__ dst,
    float* __restrict__ agg)
{
    __shared__ __align__(16) float Wl[DD * DD];
    __shared__ __align__(16) float bl[DD];
    int tid = threadIdx.x;
    for (int i = tid; i < DD * DD / 4; i += 256)
        ((float4*)Wl)[i] = ((const float4*)W)[i];
    if (tid < DD / 4) ((float4*)bl)[tid] = ((const float4*)bias)[tid];
    __syncthreads();
    int e = blockIdx.x * 256 + tid;
    int s = src[e], d = dst[e];
    float av[DD];
    const float4* earow = (const float4*)(ea + (size_t)e * DD);
#pragma unroll
    for (int i = 0; i < DD / 4; ++i) {
        float4 t = earow[i];
        av[4*i] = t.x; av[4*i+1] = t.y; av[4*i+2] = t.z; av[4*i+3] = t.w;
    }
    const float4* hrow = (const float4*)(h + (size_t)s * DD);
    float* arow = agg + (size_t)d * DD;
    for (int c4 = 0; c4 < DD / 4; ++c4) {
        float4 acc = ((float4*)bl)[c4];
#pragma unroll
        for (int k = 0; k < DD; ++k) {
            float4 w = ((float4*)Wl)[k * (DD/4) + c4];
            acc.x = fmaf(av[k], w.x, acc.x);
            acc.y = fmaf(av[k], w.y, acc.y);
            acc.z = fmaf(av[k], w.z, acc.z);
            acc.w = fmaf(av[k], w.w, acc.w);
        }
        float4 hv = hrow[c4];
        atomicAdd(arow + c4*4 + 0, fmaxf(hv.x + acc.x, 0.f));
        atomicAdd(arow + c4*4 + 1, fmaxf(hv.y + acc.y, 0.f));
        atomicAdd(arow + c4*4 + 2, fmaxf(hv.z + acc.z, 0.f));
        atomicAdd(arow + c4*4 + 3, fmaxf(hv.w + acc.w, 0.f));
    }
}
// fallback norm_pool (no bf16 mirror)
__global__ __launch_bounds__(256) void k_norm_pool_fb(
    const float* __restrict__ z, const float* __restrict__ stats,
    const float* __restrict__ gamma, const float* __restrict__ beta,
    const int* __restrict__ batch, float* __restrict__ hout,
    float* __restrict__ pooled, int l)
{
    int wave = (blockIdx.x * 256 + threadIdx.x) >> 6;
    int lane = threadIdx.x & 63;
    int n0 = wave * 64;
    if (n0 >= NN) return;
    int n1 = n0 + 64; if (n1 > NN) n1 = NN;
    float mu  = stats[lane] * (1.0f / NN);
    float var = stats[64 + lane] * (1.0f / NN) - mu * mu;
    float rstd = rsqrtf(var + 1e-5f);
    float sc = gamma[l * DD + lane] * rstd;
    float sh = beta[l * DD + lane] - sc * mu;
    int gcur = batch[n0];
    float acc = 0.f;
    for (int n = n0; n < n1; ++n) {
        float hv = fmaf(z[(size_t)n * DD + lane], sc, sh);
        hout[(size_t)n * DD + lane] = hv;
        int g = batch[n];
        if (g != gcur) {
            atomicAdd(&pooled[(size_t)gcur * (3 * DD) + l * DD + lane], acc);
            gcur = g; acc = 0.f;
        }
        acc += hv;
    }
    atomicAdd(&pooled[(size_t)gcur * (3 * DD) + l * DD + lane], acc);
}

// ----------------------------------------------------------------------------
extern "C" void kernel_launch(void* const* d_in, const int* in_sizes, int n_in,
                              void* d_out, int out_size, void* d_ws, size_t ws_size,
                              hipStream_t stream) {
    const float* x     = (const float*)d_in[0];
    const float* ea    = (const float*)d_in[1];
    const float* We    = (const float*)d_in[2];
    const float* be    = (const float*)d_in[3];
    const float* W1    = (const float*)d_in[4];
    const float* b1    = (const float*)d_in[5];
    const float* W2    = (const float*)d_in[6];
    const float* b2    = (const float*)d_in[7];
    const float* gamma = (const float*)d_in[8];
    const float* beta  = (const float*)d_in[9];
    const int*   eidx  = (const int*)d_in[10];
    const int*   batch = (const int*)d_in[11];
    const int* src = eidx;
    const int* dst = eidx + NE;

    float* out_pool = (float*)d_out;                  // [NG, 3*DD]
    float* out_h    = out_pool + POOLED_F;            // [NN, DD]

    const int exp_sizes[12] = {6400000, 102400000, 12288, 192, 12288, 192,
                               12288, 192, 192, 192, 3200000, 100000};
    bool ok = (n_in == 12);
    for (int i = 0; ok && i < 12; ++i) ok = (in_sizes[i] == exp_sizes[i]);
    if (!ok) {
        k_sentinel<<<1, 64, 0, stream>>>((float*)d_out, 16384.0f);
        return;
    }

    u16*   msgb   = (u16*)d_ws;                            // 3*NE*DD bf16 (614 MB)
    float* zbuf   = (float*)(msgb + (size_t)3 * NE * DD);  // NN*DD f32
    float* stats  = zbuf + (size_t)NN * DD;                // STATS_F
    int*   rowptr = (int*)(stats + STATS_F);               // NN+1
    int*   cursor = rowptr + (NN + 1);                     // NN
    int*   counts = cursor + NN;                           // NN
    int*   epos   = counts + NN;                           // NE
    int*   psrc   = epos + NE;                             // NE
    int*   bsum   = psrc + NE;                             // 256
    int*   boff   = bsum + 256;                            // 256
    u16*   hb16   = (u16*)(boff + 256);                    // NN*DD bf16 (12.8 MB)
    size_t needed_fast = (size_t)3 * NE * DD * 2
                       + ((size_t)NN * DD + STATS_F) * 4
                       + ((size_t)(NN + 1) + NN + NN + NE + NE + 512) * 4
                       + (size_t)NN * DD * 2;

    k_zero<<<(POOLED_F + 255) / 256, 256, 0, stream>>>(out_pool, POOLED_F);

    if (ws_size >= needed_fast) {
        k_zero<<<(STATS_F + 255) / 256, 256, 0, stream>>>(stats, STATS_F);
        k_zeroi<<<(NN + 255) / 256, 256, 0, stream>>>(counts, NN);
        k_hist<<<NE / 256, 256, 0, stream>>>(dst, counts);
        k_scanA<<<SCAN_NB, 512, 0, stream>>>(counts, bsum);
        k_scanB<<<1, 256, 0, stream>>>(bsum, boff, rowptr);
        k_scanC<<<SCAN_NB, 512, 0, stream>>>(counts, boff, rowptr, cursor);
        k_scatter<<<NE / 256, 256, 0, stream>>>(src, dst, cursor, epos, psrc);

        // one fused MFMA pass computes all 3 layers' edge GEMMs (pipelined)
        k_fmsg<<<2048, 256, 0, stream>>>(ea, We, be, epos, msgb);
        // bf16 mirror of x for layer-0 gathers
        k_cvt16<<<2048, 256, 0, stream>>>(x, hb16);

        for (int l = 0; l < 3; ++l) {
            const float* hf = (l == 0) ? x : out_h;
            const u16* msg_l = msgb + (size_t)l * NE * DD;
            k_agg<<<(NN * DD + 255) / 256, 256, 0, stream>>>(msg_l, hf, hb16,
                                                             rowptr, psrc, zbuf);
            k_mlp_stats<<<2048, 256, 0, stream>>>(zbuf, W1 + l * DD * DD,
                                                  b1 + l * DD,
                                                  W2 + l * DD * DD,
                                                  b2 + l * DD,
                                                  zbuf, stats + l * 128);
            k_norm_pool<<<(NN + 255) / 256, 256, 0, stream>>>(
                zbuf, stats + l * 128, gamma, beta, batch, out_h, hb16,
                out_pool, l);
        }
    } else {
        // fallback: round-8 proven f32 path
        float* agg2   = (float*)d_ws;
        float* stats2 = agg2 + (size_t)NN * DD;
        if (ws_size < ((size_t)NN * DD + STATS_F) * sizeof(float)) {
            k_sentinel<<<1, 64, 0, stream>>>((float*)d_out, 32768.0f);
            return;
        }
        k_zero<<<(STATS_F + 255) / 256, 256, 0, stream>>>(stats2, STATS_F);
        for (int l = 0; l < 3; ++l) {
            const float* h = (l == 0) ? x : out_h;
            k_copy<<<2048, 256, 0, stream>>>(h, agg2);
            k_edge<<<NE / 256, 256, 0, stream>>>(ea, h, We + l * DD * DD,
                                                 be + l * DD, src, dst, agg2);
            k_mlp_stats<<<2048, 256, 0, stream>>>(agg2, W1 + l * DD * DD,
                                                  b1 + l * DD,
                                                  W2 + l * DD * DD,
                                                  b2 + l * DD,
                                                  agg2, stats2 + l * 128);
            k_norm_pool_fb<<<(NN + 255) / 256, 256, 0, stream>>>(
                agg2, stats2 + l * 128, gamma, beta, batch, out_h, out_pool, l);
        }
    }
}

// Round 23
// 1036.404 us; speedup vs baseline: 1.0171x; 1.0171x over previous
//
#include <hip/hip_runtime.h>
#include <hip/hip_bf16.h>

#define NN 100000
#define NE 1600000
#define DD 64
#define NG 512
#define POOLED_F (NG * 3 * DD)   // 98304
#define STATS_F  (3 * 128)
#define SCAN_NB 196              // 196 * 512 = 100352 >= NN

typedef unsigned short u16;
typedef __attribute__((ext_vector_type(8))) short bf16x8;
typedef __attribute__((ext_vector_type(4))) float f32x4;

__device__ __forceinline__ float bf2f(u16 u) {
    return __uint_as_float(((unsigned)u) << 16);
}
__device__ __forceinline__ u16 f2bf(float f) {  // RNE
    unsigned b = __float_as_uint(f);
    return (u16)((b + 0x7FFFu + ((b >> 16) & 1u)) >> 16);
}

__global__ __launch_bounds__(256) void k_zero(float* __restrict__ p, int n) {
    int i = blockIdx.x * 256 + threadIdx.x;
    if (i < n) p[i] = 0.f;
}
__global__ __launch_bounds__(256) void k_zeroi(int* __restrict__ p, int n) {
    int i = blockIdx.x * 256 + threadIdx.x;
    if (i < n) p[i] = 0;
}
__global__ __launch_bounds__(256) void k_sentinel(float* out, float val) {
    if (threadIdx.x == 0 && blockIdx.x == 0) out[0] = val;
}

// ---------------------------------------------------------------- CSR build
__global__ __launch_bounds__(256) void k_hist(const int* __restrict__ dst,
                                              int* __restrict__ counts) {
    int e = blockIdx.x * 256 + threadIdx.x;
    if (e < NE) atomicAdd(&counts[dst[e]], 1);
}

__global__ __launch_bounds__(512) void k_scanA(const int* __restrict__ counts,
                                               int* __restrict__ bsum) {
    __shared__ int red[512];
    int tid = threadIdx.x;
    int idx = blockIdx.x * 512 + tid;
    red[tid] = (idx < NN) ? counts[idx] : 0;
    __syncthreads();
    for (int w = 256; w > 0; w >>= 1) {
        if (tid < w) red[tid] += red[tid + w];
        __syncthreads();
    }
    if (tid == 0) bsum[blockIdx.x] = red[0];
}

__global__ __launch_bounds__(256) void k_scanB(const int* __restrict__ bsum,
                                               int* __restrict__ boff,
                                               int* __restrict__ rowptr) {
    __shared__ int sh[256];
    int tid = threadIdx.x;
    int v = (tid < SCAN_NB) ? bsum[tid] : 0;
    sh[tid] = v;
    __syncthreads();
    for (int off = 1; off < 256; off <<= 1) {
        int t = (tid >= off) ? sh[tid - off] : 0;
        __syncthreads();
        sh[tid] += t;
        __syncthreads();
    }
    if (tid < SCAN_NB) boff[tid] = sh[tid] - v;   // exclusive
    if (tid == SCAN_NB - 1) rowptr[NN] = sh[tid]; // total
}

__global__ __launch_bounds__(512) void k_scanC(const int* __restrict__ counts,
                                               const int* __restrict__ boff,
                                               int* __restrict__ rowptr,
                                               int* __restrict__ cursor) {
    __shared__ int sh[512];
    int tid = threadIdx.x;
    int idx = blockIdx.x * 512 + tid;
    int v = (idx < NN) ? counts[idx] : 0;
    sh[tid] = v;
    __syncthreads();
    for (int off = 1; off < 512; off <<= 1) {
        int t = (tid >= off) ? sh[tid - off] : 0;
        __syncthreads();
        sh[tid] += t;
        __syncthreads();
    }
    if (idx < NN) {
        int r = boff[blockIdx.x] + sh[tid] - v;
        rowptr[idx] = r;
        cursor[idx] = r;
    }
}

__global__ __launch_bounds__(256) void k_scatter(const int* __restrict__ src,
                                                 const int* __restrict__ dst,
                                                 int* __restrict__ cursor,
                                                 int* __restrict__ epos,
                                                 int* __restrict__ psrc) {
    int e = blockIdx.x * 256 + threadIdx.x;
    if (e >= NE) return;
    int pos = atomicAdd(&cursor[dst[e]], 1);
    epos[e] = pos;
    psrc[pos] = src[e];
}

// --------------------------------------------- fused 3-layer msg GEMM, MFMA
// software-pipelined (r20-proven: 277 -> 243 us)
__global__ __launch_bounds__(256) void k_fmsg(
    const float* __restrict__ ea, const float* __restrict__ We,
    const float* __restrict__ be, const int* __restrict__ epos,
    u16* __restrict__ msgb)
{
    __shared__ u16 stage[4][16][72];   // 9216 B; row stride 144 B (16B-mult)
    int tid = threadIdx.x;
    int wv = tid >> 6, lane = tid & 63;
    int lg = lane >> 4, lr = lane & 15;

    bf16x8 wf[3][4][2];
    float bias[3][4];
#pragma unroll
    for (int l = 0; l < 3; ++l)
#pragma unroll
        for (int cb = 0; cb < 4; ++cb) {
#pragma unroll
            for (int kh = 0; kh < 2; ++kh) {
                bf16x8 f;
#pragma unroll
                for (int j = 0; j < 8; ++j) {
                    int k = kh * 32 + lg * 8 + j;
                    f[j] = (short)f2bf(We[l * 4096 + k * 64 + cb * 16 + lr]);
                }
                wf[l][cb][kh] = f;
            }
            bias[l][cb] = be[l * 64 + cb * 16 + lr];
        }

    const int ngroups = NE / 16;   // 100000
    const int stride = gridDim.x * 4;
    int g = blockIdx.x * 4 + wv;
    if (g >= ngroups) return;

    float4 t0a, t1a, t0b, t1b;
    {
        const float4* ap =
            (const float4*)(ea + (size_t)((g * 16) + lr) * DD + lg * 8);
        t0a = ap[0]; t1a = ap[1];          // kh = 0
        t0b = ap[8]; t1b = ap[9];          // kh = 1
    }

    while (g < ngroups) {
        int gn = g + stride;
        bf16x8 af[2];
        {
            bf16x8 f;
            f[0] = (short)f2bf(t0a.x); f[1] = (short)f2bf(t0a.y);
            f[2] = (short)f2bf(t0a.z); f[3] = (short)f2bf(t0a.w);
            f[4] = (short)f2bf(t1a.x); f[5] = (short)f2bf(t1a.y);
            f[6] = (short)f2bf(t1a.z); f[7] = (short)f2bf(t1a.w);
            af[0] = f;
            f[0] = (short)f2bf(t0b.x); f[1] = (short)f2bf(t0b.y);
            f[2] = (short)f2bf(t0b.z); f[3] = (short)f2bf(t0b.w);
            f[4] = (short)f2bf(t1b.x); f[5] = (short)f2bf(t1b.y);
            f[6] = (short)f2bf(t1b.z); f[7] = (short)f2bf(t1b.w);
            af[1] = f;
        }
        if (gn < ngroups) {
            const float4* ap =
                (const float4*)(ea + (size_t)((gn * 16) + lr) * DD + lg * 8);
            t0a = ap[0]; t1a = ap[1];
            t0b = ap[8]; t1b = ap[9];
        }

        int ebase = g * 16;
#pragma unroll
        for (int l = 0; l < 3; ++l) {
#pragma unroll
            for (int cb = 0; cb < 4; ++cb) {
                f32x4 acc = {0.f, 0.f, 0.f, 0.f};
                acc = __builtin_amdgcn_mfma_f32_16x16x32_bf16(
                          af[0], wf[l][cb][0], acc, 0, 0, 0);
                acc = __builtin_amdgcn_mfma_f32_16x16x32_bf16(
                          af[1], wf[l][cb][1], acc, 0, 0, 0);
#pragma unroll
                for (int i = 0; i < 4; ++i)
                    stage[wv][lg * 4 + i][cb * 16 + lr] =
                        f2bf(acc[i] + bias[l][cb]);
            }
#pragma unroll
            for (int p = 0; p < 2; ++p) {
                int row = p * 8 + (lane >> 3), chunk = lane & 7;
                uint4 v = *(const uint4*)&stage[wv][row][chunk * 8];
                int pos = epos[ebase + row];
                *(uint4*)(msgb + ((size_t)l * NE + pos) * DD + chunk * 8) = v;
            }
        }
        g = gn;
    }
}

// ---------------------------------------------------------------- aggregate
// lean gather kernel, unroll 4, f32 h (measured best of 6 variants)
__global__ __launch_bounds__(256) void k_agg(
    const u16* __restrict__ msgb, const float* __restrict__ h,
    const int* __restrict__ rowptr, const int* __restrict__ psrc,
    float* __restrict__ agg)
{
    int node = (blockIdx.x * 256 + threadIdx.x) >> 6;
    int lane = threadIdx.x & 63;
    if (node >= NN) return;
    int beg = rowptr[node], end = rowptr[node + 1];
    float acc = h[(size_t)node * DD + lane];
    int j = beg;
    for (; j + 3 < end; j += 4) {
        int s0 = psrc[j], s1 = psrc[j + 1], s2 = psrc[j + 2], s3 = psrc[j + 3];
        float m0 = h[(size_t)s0 * DD + lane] + bf2f(msgb[(size_t)j * DD + lane]);
        float m1 = h[(size_t)s1 * DD + lane] + bf2f(msgb[(size_t)(j + 1) * DD + lane]);
        float m2 = h[(size_t)s2 * DD + lane] + bf2f(msgb[(size_t)(j + 2) * DD + lane]);
        float m3 = h[(size_t)s3 * DD + lane] + bf2f(msgb[(size_t)(j + 3) * DD + lane]);
        acc += fmaxf(m0, 0.f) + fmaxf(m1, 0.f) + fmaxf(m2, 0.f) + fmaxf(m3, 0.f);
    }
    for (; j < end; ++j) {
        int s = psrc[j];
        acc += fmaxf(h[(size_t)s * DD + lane] + bf2f(msgb[(size_t)j * DD + lane]), 0.f);
    }
    agg[(size_t)node * DD + lane] = acc;
}

// ---------------- MLP (lane=channel, W in LDS) with fused BN stats
__global__ __launch_bounds__(256) void k_mlp_stats(
    const float* __restrict__ in,
    const float* __restrict__ W1, const float* __restrict__ b1,
    const float* __restrict__ W2, const float* __restrict__ b2,
    float* __restrict__ z, float* __restrict__ stats)
{
    __shared__ __align__(16) float W1l[DD * DD];   // [k*64 + c]
    __shared__ __align__(16) float W2l[DD * DD];
    __shared__ float zin[4][DD];
    __shared__ float red[512];
    int tid = threadIdx.x, wv = tid >> 6, lane = tid & 63;
    for (int i = tid; i < DD * DD / 4; i += 256) {
        ((float4*)W1l)[i] = ((const float4*)W1)[i];
        ((float4*)W2l)[i] = ((const float4*)W2)[i];
    }
    float b1c = b1[lane], b2c = b2[lane];
    __syncthreads();

    float s = 0.f, s2 = 0.f;
    int wid = blockIdx.x * 4 + wv, nw = gridDim.x * 4;
    for (int node = wid; node < NN; node += nw) {
        zin[wv][lane] = in[(size_t)node * DD + lane];   // wave-local broadcast
        float z1 = b1c;
#pragma unroll
        for (int k = 0; k < DD; ++k)
            z1 = fmaf(zin[wv][k], W1l[k * DD + lane], z1);
        z1 = fmaxf(z1, 0.f);
        zin[wv][lane] = z1;                              // in-wave ordered
        float z2 = b2c;
#pragma unroll
        for (int k = 0; k < DD; ++k)
            z2 = fmaf(zin[wv][k], W2l[k * DD + lane], z2);
        z2 = fmaxf(z2, 0.f);
        z[(size_t)node * DD + lane] = z2;
        s += z2;
        s2 = fmaf(z2, z2, s2);
    }
    red[tid] = s; red[256 + tid] = s2;
    __syncthreads();
    if (tid < 64) {
        float a = red[tid] + red[64 + tid] + red[128 + tid] + red[192 + tid];
        float b = red[256 + tid] + red[320 + tid] + red[384 + tid] + red[448 + tid];
        atomicAdd(&stats[tid], a);
        atomicAdd(&stats[64 + tid], b);
    }
}

// ------------------- norm + pool (sorted batch), bnfinal folded in
__global__ __launch_bounds__(256) void k_norm_pool(
    const float* __restrict__ z, const float* __restrict__ stats,
    const float* __restrict__ gamma, const float* __restrict__ beta,
    const int* __restrict__ batch, float* __restrict__ hout,
    float* __restrict__ pooled, int l)
{
    int wave = (blockIdx.x * 256 + threadIdx.x) >> 6;
    int lane = threadIdx.x & 63;
    int n0 = wave * 64;
    if (n0 >= NN) return;
    int n1 = n0 + 64; if (n1 > NN) n1 = NN;

    float mu  = stats[lane] * (1.0f / NN);
    float var = stats[64 + lane] * (1.0f / NN) - mu * mu;
    float rstd = rsqrtf(var + 1e-5f);
    float sc = gamma[l * DD + lane] * rstd;
    float sh = beta[l * DD + lane] - sc * mu;

    int gcur = batch[n0];
    float acc = 0.f;
    for (int n = n0; n < n1; ++n) {
        float hv = fmaf(z[(size_t)n * DD + lane], sc, sh);
        hout[(size_t)n * DD + lane] = hv;
        int g = batch[n];
        if (g != gcur) {
            atomicAdd(&pooled[(size_t)gcur * (3 * DD) + l * DD + lane], acc);
            gcur = g; acc = 0.f;
        }
        acc += hv;
    }
    atomicAdd(&pooled[(size_t)gcur * (3 * DD) + l * DD + lane], acc);
}

// ---------------------------------------------------------------- fallback
__global__ __launch_bounds__(256) void k_copy(const float* __restrict__ src,
                                              float* __restrict__ agg) {
    int total = NN * DD / 4;
    for (int i = blockIdx.x * 256 + threadIdx.x; i < total; i += gridDim.x * 256)
        ((float4*)agg)[i] = ((const float4*)src)[i];
}
__global__ __launch_bounds__(256) void k_edge(
    const float* __restrict__ ea, const float* __restrict__ h,
    const float* __restrict__ W, const float* __restrict__ bias,
    const int* __restrict__ src, const int* __restrict__ dst,
    float* __restrict__ agg)
{
    __shared__ __align__(16) float Wl[DD * DD];
    __shared__ __align__(16) float bl[DD];
    int tid = threadIdx.x;
    for (int i = tid; i < DD * DD / 4; i += 256)
        ((float4*)Wl)[i] = ((const float4*)W)[i];
    if (tid < DD / 4) ((float4*)bl)[tid] = ((const float4*)bias)[tid];
    __syncthreads();
    int e = blockIdx.x * 256 + tid;
    int s = src[e], d = dst[e];
    float av[DD];
    const float4* earow = (const float4*)(ea + (size_t)e * DD);
#pragma unroll
    for (int i = 0; i < DD / 4; ++i) {
        float4 t = earow[i];
        av[4*i] = t.x; av[4*i+1] = t.y; av[4*i+2] = t.z; av[4*i+3] = t.w;
    }
    const float4* hrow = (const float4*)(h + (size_t)s * DD);
    float* arow = agg + (size_t)d * DD;
    for (int c4 = 0; c4 < DD / 4; ++c4) {
        float4 acc = ((float4*)bl)[c4];
#pragma unroll
        for (int k = 0; k < DD; ++k) {
            float4 w = ((float4*)Wl)[k * (DD/4) + c4];
            acc.x = fmaf(av[k], w.x, acc.x);
            acc.y = fmaf(av[k], w.y, acc.y);
            acc.z = fmaf(av[k], w.z, acc.z);
            acc.w = fmaf(av[k], w.w, acc.w);
        }
        float4 hv = hrow[c4];
        atomicAdd(arow + c4*4 + 0, fmaxf(hv.x + acc.x, 0.f));
        atomicAdd(arow + c4*4 + 1, fmaxf(hv.y + acc.y, 0.f));
        atomicAdd(arow + c4*4 + 2, fmaxf(hv.z + acc.z, 0.f));
        atomicAdd(arow + c4*4 + 3, fmaxf(hv.w + acc.w, 0.f));
    }
}

// ----------------------------------------------------------------------------
extern "C" void kernel_launch(void* const* d_in, const int* in_sizes, int n_in,
                              void* d_out, int out_size, void* d_ws, size_t ws_size,
                              hipStream_t stream) {
    const float* x     = (const float*)d_in[0];
    const float* ea    = (const float*)d_in[1];
    const float* We    = (const float*)d_in[2];
    const float* be    = (const float*)d_in[3];
    const float* W1    = (const float*)d_in[4];
    const float* b1    = (const float*)d_in[5];
    const float* W2    = (const float*)d_in[6];
    const float* b2    = (const float*)d_in[7];
    const float* gamma = (const float*)d_in[8];
    const float* beta  = (const float*)d_in[9];
    const int*   eidx  = (const int*)d_in[10];
    const int*   batch = (const int*)d_in[11];
    const int* src = eidx;
    const int* dst = eidx + NE;

    float* out_pool = (float*)d_out;                  // [NG, 3*DD]
    float* out_h    = out_pool + POOLED_F;            // [NN, DD]

    const int exp_sizes[12] = {6400000, 102400000, 12288, 192, 12288, 192,
                               12288, 192, 192, 192, 3200000, 100000};
    bool ok = (n_in == 12);
    for (int i = 0; ok && i < 12; ++i) ok = (in_sizes[i] == exp_sizes[i]);
    if (!ok) {
        k_sentinel<<<1, 64, 0, stream>>>((float*)d_out, 16384.0f);
        return;
    }

    u16*   msgb   = (u16*)d_ws;                            // 3*NE*DD bf16 (614 MB)
    float* zbuf   = (float*)(msgb + (size_t)3 * NE * DD);  // NN*DD f32
    float* stats  = zbuf + (size_t)NN * DD;                // STATS_F
    int*   rowptr = (int*)(stats + STATS_F);               // NN+1
    int*   cursor = rowptr + (NN + 1);                     // NN
    int*   counts = cursor + NN;                           // NN
    int*   epos   = counts + NN;                           // NE
    int*   psrc   = epos + NE;                             // NE
    int*   bsum   = psrc + NE;                             // 256
    int*   boff   = bsum + 256;                            // 256
    size_t needed_fast = (size_t)3 * NE * DD * 2
                       + ((size_t)NN * DD + STATS_F) * 4
                       + ((size_t)(NN + 1) + NN + NN + NE + NE + 512) * 4;

    k_zero<<<(POOLED_F + 255) / 256, 256, 0, stream>>>(out_pool, POOLED_F);

    if (ws_size >= needed_fast) {
        k_zero<<<(STATS_F + 255) / 256, 256, 0, stream>>>(stats, STATS_F);
        k_zeroi<<<(NN + 255) / 256, 256, 0, stream>>>(counts, NN);
        k_hist<<<NE / 256, 256, 0, stream>>>(dst, counts);
        k_scanA<<<SCAN_NB, 512, 0, stream>>>(counts, bsum);
        k_scanB<<<1, 256, 0, stream>>>(bsum, boff, rowptr);
        k_scanC<<<SCAN_NB, 512, 0, stream>>>(counts, boff, rowptr, cursor);
        k_scatter<<<NE / 256, 256, 0, stream>>>(src, dst, cursor, epos, psrc);

        // one fused MFMA pass computes all 3 layers' edge GEMMs (pipelined)
        k_fmsg<<<2048, 256, 0, stream>>>(ea, We, be, epos, msgb);

        for (int l = 0; l < 3; ++l) {
            const float* h = (l == 0) ? x : out_h;
            const u16* msg_l = msgb + (size_t)l * NE * DD;
            k_agg<<<(NN * DD + 255) / 256, 256, 0, stream>>>(msg_l, h, rowptr,
                                                             psrc, zbuf);
            k_mlp_stats<<<2048, 256, 0, stream>>>(zbuf, W1 + l * DD * DD,
                                                  b1 + l * DD,
                                                  W2 + l * DD * DD,
                                                  b2 + l * DD,
                                                  zbuf, stats + l * 128);
            k_norm_pool<<<(NN + 255) / 256, 256, 0, stream>>>(
                zbuf, stats + l * 128, gamma, beta, batch, out_h, out_pool, l);
        }
    } else {
        // fallback: round-8 proven f32 path
        float* agg2   = (float*)d_ws;
        float* stats2 = agg2 + (size_t)NN * DD;
        if (ws_size < ((size_t)NN * DD + STATS_F) * sizeof(float)) {
            k_sentinel<<<1, 64, 0, stream>>>((float*)d_out, 32768.0f);
            return;
        }
        k_zero<<<(STATS_F + 255) / 256, 256, 0, stream>>>(stats2, STATS_F);
        for (int l = 0; l < 3; ++l) {
            const float* h = (l == 0) ? x : out_h;
            k_copy<<<2048, 256, 0, stream>>>(h, agg2);
            k_edge<<<NE / 256, 256, 0, stream>>>(ea, h, We + l * DD * DD,
                                                 be + l * DD, src, dst, agg2);
            k_mlp_stats<<<2048, 256, 0, stream>>>(agg2, W1 + l * DD * DD,
                                                  b1 + l * DD,
                                                  W2 + l * DD * DD,
                                                  b2 + l * DD,
                                                  agg2, stats2 + l * 128);
            k_norm_pool<<<(NN + 255) / 256, 256, 0, stream>>>(
                agg2, stats2 + l * 128, gamma, beta, batch, out_h, out_pool, l);
        }
    }
}